// Round 2
// baseline (3220.538 us; speedup 1.0000x reference)
//
#include <hip/hip_runtime.h>
#include <hip/hip_bf16.h>

using bf16 = __hip_bfloat16;

static __device__ __forceinline__ float b2f(bf16 v) { return __bfloat162float(v); }
static __device__ __forceinline__ bf16  f2b(float v) { return __float2bfloat16(v); }
static __device__ __forceinline__ float toF(float v) { return v; }
static __device__ __forceinline__ float toF(bf16 v)  { return __bfloat162float(v); }
static __device__ __forceinline__ void stF(float* p, float v) { *p = v; }
static __device__ __forceinline__ void stF(bf16* p,  float v) { *p = f2b(v); }

// ---------------- LN1 + DWT: x fp32 (2,256,256,180) -> xd bf16 (2,128,128,720) ----------------
__global__ __launch_bounds__(256) void ln_dwt_kernel(
    const float* __restrict__ x, const float* __restrict__ w, const float* __restrict__ bia,
    bf16* __restrict__ xd)
{
  __shared__ float nrm[4][180];
  int blk = blockIdx.x;                 // b*16384 + i*128 + j  (half-res coords)
  int j = blk & 127; int i = (blk >> 7) & 127; int b = blk >> 14;
  int wave = threadIdx.x >> 6, lane = threadIdx.x & 63;
  int ty = wave >> 1, tx = wave & 1;    // wave 0..3 -> tokens a,bb,cc,dd
  size_t tok = (size_t)b * 65536 + (size_t)(2 * i + ty) * 256 + (size_t)(2 * j + tx);
  const float* xp = x + tok * 180;
  float v0 = xp[lane];
  float v1 = xp[lane + 64];
  float v2 = (lane < 52) ? xp[lane + 128] : 0.f;
  float s = v0 + v1 + v2, ss = v0 * v0 + v1 * v1 + v2 * v2;
  #pragma unroll
  for (int m = 32; m; m >>= 1) { s += __shfl_xor(s, m); ss += __shfl_xor(ss, m); }
  float mu = s * (1.f / 180.f);
  float rstd = rsqrtf(ss * (1.f / 180.f) - mu * mu + 1e-5f);
  nrm[wave][lane]      = (v0 - mu) * rstd * w[lane]      + bia[lane];
  nrm[wave][lane + 64] = (v1 - mu) * rstd * w[lane + 64] + bia[lane + 64];
  if (lane < 52)
    nrm[wave][lane + 128] = (v2 - mu) * rstd * w[lane + 128] + bia[lane + 128];
  __syncthreads();
  bf16* op = xd + (size_t)blk * 720;
  for (int o = threadIdx.x; o < 720; o += 256) {
    int g = o / 180, c = o % 180;
    float a = nrm[0][c], bb = nrm[1][c], cc = nrm[2][c], dd = nrm[3][c];
    float r = (g == 0) ? (a + bb + cc + dd)
            : (g == 1) ? (-a - bb + cc + dd)
            : (g == 2) ? (-a + bb - cc + dd)
                       : (a - bb - cc + dd);
    op[o] = f2b(r * 0.5f);
  }
}

// ---------------- plain LN: x1 bf16 (131072,180) -> y bf16 ----------------
__global__ __launch_bounds__(256) void ln_kernel(
    const bf16* __restrict__ x, const float* __restrict__ w, const float* __restrict__ bia,
    bf16* __restrict__ y)
{
  int wave = threadIdx.x >> 6, lane = threadIdx.x & 63;
  size_t tok = (size_t)blockIdx.x * 4 + wave;
  const bf16* xp = x + tok * 180;
  float v0 = b2f(xp[lane]);
  float v1 = b2f(xp[lane + 64]);
  float v2 = (lane < 52) ? b2f(xp[lane + 128]) : 0.f;
  float s = v0 + v1 + v2, ss = v0 * v0 + v1 * v1 + v2 * v2;
  #pragma unroll
  for (int m = 32; m; m >>= 1) { s += __shfl_xor(s, m); ss += __shfl_xor(ss, m); }
  float mu = s * (1.f / 180.f);
  float rstd = rsqrtf(ss * (1.f / 180.f) - mu * mu + 1e-5f);
  bf16* yp = y + tok * 180;
  yp[lane]      = f2b((v0 - mu) * rstd * w[lane]      + bia[lane]);
  yp[lane + 64] = f2b((v1 - mu) * rstd * w[lane + 64] + bia[lane + 64]);
  if (lane < 52)
    yp[lane + 128] = f2b((v2 - mu) * rstd * w[lane + 128] + bia[lane + 128]);
}

// ---------------- generic GEMM: out = ep(A@W + bias [, res]) ----------------
// A: MxK bf16 row-major, W: KxN fp32 row-major. EP: 0=none, 1=+res, 2=gelu(exact)
template <int EP, typename TRes, typename TOut>
__global__ __launch_bounds__(256) void gemm_kernel(
    const bf16* __restrict__ A, const float* __restrict__ W,
    const float* __restrict__ bias, const TRes* __restrict__ res,
    TOut* __restrict__ out, int M, int N, int K)
{
  __shared__ float As[16][64];
  __shared__ float Bs[16][65];
  int tid = threadIdx.x;
  int tx = tid & 15, ty = tid >> 4;
  int m0 = blockIdx.x * 64;
  int n0 = blockIdx.y * 64;
  float c[4][4] = {};
  int arow = tid >> 2;            // 0..63
  int acol = (tid & 3) * 4;       // 0,4,8,12
  int wrow = tid >> 4;            // 0..15
  int wcol = (tid & 15) * 4;      // 0..60
  for (int k0 = 0; k0 < K; k0 += 16) {
    {
      const bf16* ap = A + (size_t)(m0 + arow) * K + (k0 + acol);
      #pragma unroll
      for (int i = 0; i < 4; i++) {
        int kk = k0 + acol + i;
        As[acol + i][arow] = (kk < K) ? b2f(ap[i]) : 0.f;
      }
    }
    {
      int kk = k0 + wrow;
      const float* wp = W + (size_t)kk * N + (n0 + wcol);
      #pragma unroll
      for (int i = 0; i < 4; i++) {
        int n = n0 + wcol + i;
        Bs[wrow][wcol + i] = (kk < K && n < N) ? wp[i] : 0.f;
      }
    }
    __syncthreads();
    #pragma unroll
    for (int kk = 0; kk < 16; kk++) {
      float a[4], bvals[4];
      #pragma unroll
      for (int i = 0; i < 4; i++) a[i] = As[kk][ty * 4 + i];
      #pragma unroll
      for (int jj = 0; jj < 4; jj++) bvals[jj] = Bs[kk][tx * 4 + jj];
      #pragma unroll
      for (int i = 0; i < 4; i++)
        #pragma unroll
        for (int jj = 0; jj < 4; jj++)
          c[i][jj] += a[i] * bvals[jj];
    }
    __syncthreads();
  }
  #pragma unroll
  for (int i = 0; i < 4; i++) {
    int row = m0 + ty * 4 + i;
    #pragma unroll
    for (int jj = 0; jj < 4; jj++) {
      int col = n0 + tx * 4 + jj;
      if (col >= N) continue;
      float v = c[i][jj] + bias[col];
      if constexpr (EP == 1) v += toF(res[(size_t)row * N + col]);
      if constexpr (EP == 2) v = 0.5f * v * (1.f + erff(v * 0.70710678118654752f));
      stF(&out[(size_t)row * N + col], v);
    }
  }
}

// ---------------- attention: one block per (window, head) ----------------
// q,k: bf16 (2,128,128,180), v: bf16 (2,128,128,720) ; xw out bf16: (2,128,128,720)
__global__ __launch_bounds__(256) void attn_kernel(
    const bf16* __restrict__ q, const bf16* __restrict__ k, const bf16* __restrict__ v,
    const int* __restrict__ rpi, const float* __restrict__ rpb, bf16* __restrict__ xw)
{
  __shared__ float q_lds[64 * 30];
  __shared__ float s_lds[64 * 144];
  __shared__ float rowinv[64];
  __shared__ bf16  v_lds[72 * 120];
  const float scale = 0.18257418583505536f;  // 30^-0.5
  int blk = blockIdx.x;
  int hh = blk % 6; int wid = blk / 6;
  int wj = wid & 15; int wi = (wid >> 4) & 15; int b = wid >> 8;
  int tid = threadIdx.x;

  // stage q (pre-scaled)
  for (int e = tid; e < 1920; e += 256) {
    int r = e / 30, dd = e % 30;
    int gy = wi * 8 + (r >> 3), gx = wj * 8 + (r & 7);
    q_lds[e] = scale * b2f(q[((size_t)b * 16384 + (size_t)gy * 128 + gx) * 180 + hh * 30 + dd]);
  }
  __syncthreads();

  // scores = q.k^T + bias  (OOB halo rows: score = bias only)
  for (int idx = tid; idx < 9216; idx += 256) {
    int r = idx / 144, kk = idx % 144;
    int ky = kk / 12, kx = kk % 12;
    int gy = wi * 8 - 4 + ky, gx = wj * 8 - 4 + kx;
    float acc = 0.f;
    if (gy >= 0 && gy < 128 && gx >= 0 && gx < 128) {
      const bf16* kp = k + ((size_t)b * 16384 + (size_t)gy * 128 + gx) * 180 + hh * 30;
      const float* qp = q_lds + r * 30;
      #pragma unroll
      for (int dd = 0; dd < 30; dd++) acc += qp[dd] * b2f(kp[dd]);
    }
    acc += rpb[rpi[idx] * 6 + hh];
    s_lds[idx] = acc;
  }
  __syncthreads();

  // softmax per row (wave handles 16 rows)
  int wave = tid >> 6, lane = tid & 63;
  for (int r = wave * 16; r < wave * 16 + 16; r++) {
    float* row = s_lds + r * 144;
    float x0 = row[lane];
    float x1 = row[lane + 64];
    float x2 = (lane < 16) ? row[lane + 128] : -1e30f;
    float m = fmaxf(fmaxf(x0, x1), x2);
    #pragma unroll
    for (int sh = 32; sh; sh >>= 1) m = fmaxf(m, __shfl_xor(m, sh));
    float e0 = expf(x0 - m);
    float e1 = expf(x1 - m);
    float e2 = (lane < 16) ? expf(x2 - m) : 0.f;
    row[lane] = e0;
    row[lane + 64] = e1;
    if (lane < 16) row[lane + 128] = e2;
    float sum = e0 + e1 + e2;
    #pragma unroll
    for (int sh = 32; sh; sh >>= 1) sum += __shfl_xor(sum, sh);
    if (lane == 0) rowinv[r] = 1.f / sum;
  }
  __syncthreads();

  // PV: V staged in 2 chunks of 72 kv-rows
  float acc[30];
  #pragma unroll
  for (int jj = 0; jj < 30; jj++) acc[jj] = 0.f;
  for (int ck = 0; ck < 2; ck++) {
    for (int e = tid; e < 8640; e += 256) {
      int kl = e / 120, dd = e % 120;
      int kkg = ck * 72 + kl;
      int ky = kkg / 12, kx = kkg % 12;
      int gy = wi * 8 - 4 + ky, gx = wj * 8 - 4 + kx;
      bf16 val = f2b(0.f);
      if (gy >= 0 && gy < 128 && gx >= 0 && gx < 128)
        val = v[((size_t)b * 16384 + (size_t)gy * 128 + gx) * 720 + hh * 120 + dd];
      v_lds[e] = val;
    }
    __syncthreads();
    #pragma unroll
    for (int jj = 0; jj < 30; jj++) {
      int o = tid + jj * 256;
      int r = o / 120, dd = o % 120;
      const float* prow = s_lds + r * 144 + ck * 72;
      float a = acc[jj];
      for (int kl = 0; kl < 72; kl++)
        a += prow[kl] * b2f(v_lds[kl * 120 + dd]);
      acc[jj] = a;
    }
    __syncthreads();
  }
  // write o (channel = hh*120 + dd, matches v's natural channel space)
  #pragma unroll
  for (int jj = 0; jj < 30; jj++) {
    int o = tid + jj * 256;
    int r = o / 120, dd = o % 120;
    int gy = wi * 8 + (r >> 3), gx = wj * 8 + (r & 7);
    xw[((size_t)b * 16384 + (size_t)gy * 128 + gx) * 720 + hh * 120 + dd] =
        f2b(acc[jj] * rowinv[r]);
  }
}

// ---------------- IDWT: xw bf16 (2,128,128,720) -> xr bf16 (2,256,256,180) ----------------
__global__ __launch_bounds__(256) void idwt_kernel(
    const bf16* __restrict__ xw, bf16* __restrict__ xr)
{
  size_t gid = (size_t)blockIdx.x * 256 + threadIdx.x;
  if (gid >= 23592960ull) return;
  int c = (int)(gid % 180); size_t rest = gid / 180;
  int x2 = (int)(rest % 256); size_t rest2 = rest / 256;
  int y2 = (int)(rest2 % 256); int b = (int)(rest2 / 256);
  int i = y2 >> 1, j = x2 >> 1, py = y2 & 1, px = x2 & 1;
  const bf16* p = xw + ((size_t)b * 16384 + (size_t)i * 128 + j) * 720 + c;
  float ll = b2f(p[0]), lh = b2f(p[180]), hl = b2f(p[360]), hh = b2f(p[540]);
  float r;
  if (py == 0 && px == 0)      r = ll - lh - hl + hh;
  else if (py == 0)            r = ll - lh + hl - hh;
  else if (px == 0)            r = ll + lh - hl - hh;
  else                         r = ll + lh + hl + hh;
  xr[gid] = f2b(r * 0.5f);
}

extern "C" void kernel_launch(void* const* d_in, const int* in_sizes, int n_in,
                              void* d_out, int out_size, void* d_ws, size_t ws_size,
                              hipStream_t stream) {
  (void)in_sizes; (void)n_in; (void)out_size; (void)ws_size;
  const float* x      = (const float*)d_in[0];
  // d_in[1] cross_x, d_in[3] h, d_in[4] w, d_in[7..8] normc_* : unused by reference output
  const int*   rpi    = (const int*)  d_in[2];
  const float* n1w    = (const float*)d_in[5];
  const float* n1b    = (const float*)d_in[6];
  const float* q_w    = (const float*)d_in[9];
  const float* q_b    = (const float*)d_in[10];
  const float* k_w    = (const float*)d_in[11];
  const float* k_b    = (const float*)d_in[12];
  const float* v_w    = (const float*)d_in[13];
  const float* v_b    = (const float*)d_in[14];
  const float* rpb    = (const float*)d_in[15];
  const float* proj_w = (const float*)d_in[16];
  const float* proj_b = (const float*)d_in[17];
  const float* n2w    = (const float*)d_in[18];
  const float* n2b    = (const float*)d_in[19];
  const float* fc1_w  = (const float*)d_in[20];
  const float* fc1_b  = (const float*)d_in[21];
  const float* fc2_w  = (const float*)d_in[22];
  const float* fc2_b  = (const float*)d_in[23];
  float* out = (float*)d_out;

  // workspace layout (bf16 elements), ~262 MB total with lifetime reuse
  bf16* xd = (bf16*)d_ws;            // 23,592,960   (later reused: xw, then y)
  bf16* qb = xd + 23592960;          //  5,898,240
  bf16* kb = qb + 5898240;           //  5,898,240
  bf16* vb = kb + 5898240;           // 23,592,960   (later reused: xr)
  bf16* x1 = vb + 23592960;          // 23,592,960
  bf16* hb = x1 + 23592960;          // 47,185,920
  bf16* xw = xd;
  bf16* xr = vb;
  bf16* yb = xd;

  ln_dwt_kernel<<<32768, 256, 0, stream>>>(x, n1w, n1b, xd);
  gemm_kernel<0, float, bf16><<<dim3(512, 3),  256, 0, stream>>>(xd, q_w, q_b, nullptr, qb, 32768, 180, 720);
  gemm_kernel<0, float, bf16><<<dim3(512, 3),  256, 0, stream>>>(xd, k_w, k_b, nullptr, kb, 32768, 180, 720);
  gemm_kernel<0, float, bf16><<<dim3(512, 12), 256, 0, stream>>>(xd, v_w, v_b, nullptr, vb, 32768, 720, 720);
  attn_kernel<<<3072, 256, 0, stream>>>(qb, kb, vb, rpi, rpb, xw);
  idwt_kernel<<<92160, 256, 0, stream>>>(xw, xr);
  gemm_kernel<1, float, bf16><<<dim3(2048, 3), 256, 0, stream>>>(xr, proj_w, proj_b, x, x1, 131072, 180, 180);
  ln_kernel<<<32768, 256, 0, stream>>>(x1, n2w, n2b, yb);
  gemm_kernel<2, float, bf16><<<dim3(2048, 6), 256, 0, stream>>>(yb, fc1_w, fc1_b, nullptr, hb, 131072, 360, 180);
  gemm_kernel<1, bf16, float><<<dim3(2048, 3), 256, 0, stream>>>(hb, fc2_w, fc2_b, x1, out, 131072, 180, 360);
}

// Round 3
// 1167.482 us; speedup vs baseline: 2.7585x; 2.7585x over previous
//
#include <hip/hip_runtime.h>
#include <hip/hip_bf16.h>
#include <stdint.h>

using bf16 = __hip_bfloat16;
typedef __attribute__((ext_vector_type(8))) short bf16x8;
typedef __attribute__((ext_vector_type(4))) float f32x4;

static __device__ __forceinline__ float b2f(bf16 v) { return __bfloat162float(v); }
static __device__ __forceinline__ bf16  f2b(float v) { return __float2bfloat16(v); }
static __device__ __forceinline__ float toF(float v) { return v; }
static __device__ __forceinline__ float toF(bf16 v)  { return __bfloat162float(v); }
static __device__ __forceinline__ void stF(float* p, float v) { *p = v; }
static __device__ __forceinline__ void stF(bf16* p,  float v) { *p = f2b(v); }

// ---------------- weight convert: w[k][n] fp32 -> wt[n][k] bf16, k zero-padded to Kp ----
__global__ __launch_bounds__(256) void convert_wt_kernel(
    const float* __restrict__ w, bf16* __restrict__ wt, int K, int N, int Kp)
{
  int idx = blockIdx.x * 256 + threadIdx.x;
  if (idx >= N * Kp) return;
  int n = idx / Kp, k = idx % Kp;
  float v = (k < K) ? w[(size_t)k * N + n] : 0.f;
  wt[idx] = f2b(v);
}

// ---------------- LN1 + DWT: x fp32 (2,256,256,180) -> xd bf16 (2,128,128,720) ----------
__global__ __launch_bounds__(256) void ln_dwt_kernel(
    const float* __restrict__ x, const float* __restrict__ w, const float* __restrict__ bia,
    bf16* __restrict__ xd)
{
  __shared__ float nrm[4][180];
  int blk = blockIdx.x;
  int j = blk & 127; int i = (blk >> 7) & 127; int b = blk >> 14;
  int wave = threadIdx.x >> 6, lane = threadIdx.x & 63;
  int ty = wave >> 1, tx = wave & 1;
  size_t tok = (size_t)b * 65536 + (size_t)(2 * i + ty) * 256 + (size_t)(2 * j + tx);
  const float* xp = x + tok * 180;
  float v0 = xp[lane];
  float v1 = xp[lane + 64];
  float v2 = (lane < 52) ? xp[lane + 128] : 0.f;
  float s = v0 + v1 + v2, ss = v0 * v0 + v1 * v1 + v2 * v2;
  #pragma unroll
  for (int m = 32; m; m >>= 1) { s += __shfl_xor(s, m); ss += __shfl_xor(ss, m); }
  float mu = s * (1.f / 180.f);
  float rstd = rsqrtf(ss * (1.f / 180.f) - mu * mu + 1e-5f);
  nrm[wave][lane]      = (v0 - mu) * rstd * w[lane]      + bia[lane];
  nrm[wave][lane + 64] = (v1 - mu) * rstd * w[lane + 64] + bia[lane + 64];
  if (lane < 52)
    nrm[wave][lane + 128] = (v2 - mu) * rstd * w[lane + 128] + bia[lane + 128];
  __syncthreads();
  bf16* op = xd + (size_t)blk * 720;
  for (int o = threadIdx.x; o < 720; o += 256) {
    int g = o / 180, c = o % 180;
    float a = nrm[0][c], bb = nrm[1][c], cc = nrm[2][c], dd = nrm[3][c];
    float r = (g == 0) ? (a + bb + cc + dd)
            : (g == 1) ? (-a - bb + cc + dd)
            : (g == 2) ? (-a + bb - cc + dd)
                       : (a - bb - cc + dd);
    op[o] = f2b(r * 0.5f);
  }
}

// ---------------- plain LN: x1 bf16 (131072,180) -> y bf16 stride 192 (zero-padded) -----
__global__ __launch_bounds__(256) void ln_kernel(
    const bf16* __restrict__ x, const float* __restrict__ w, const float* __restrict__ bia,
    bf16* __restrict__ y)
{
  int wave = threadIdx.x >> 6, lane = threadIdx.x & 63;
  size_t tok = (size_t)blockIdx.x * 4 + wave;
  const bf16* xp = x + tok * 180;
  float v0 = b2f(xp[lane]);
  float v1 = b2f(xp[lane + 64]);
  float v2 = (lane < 52) ? b2f(xp[lane + 128]) : 0.f;
  float s = v0 + v1 + v2, ss = v0 * v0 + v1 * v1 + v2 * v2;
  #pragma unroll
  for (int m = 32; m; m >>= 1) { s += __shfl_xor(s, m); ss += __shfl_xor(ss, m); }
  float mu = s * (1.f / 180.f);
  float rstd = rsqrtf(ss * (1.f / 180.f) - mu * mu + 1e-5f);
  bf16* yp = y + tok * 192;
  yp[lane]      = f2b((v0 - mu) * rstd * w[lane]      + bia[lane]);
  yp[lane + 64] = f2b((v1 - mu) * rstd * w[lane + 64] + bia[lane + 64]);
  if (lane < 52)
    yp[lane + 128] = f2b((v2 - mu) * rstd * w[lane + 128] + bia[lane + 128]);
  else
    yp[lane + 128] = f2b(0.f);   // zero-fill cols 180..191 (GEMM K-padding)
}

// ---------------- MFMA GEMM: out = ep(A@Wt^T + bias [, res]) ----------------------------
// A: M x lda bf16 (valid k < KlimA, zeros logically beyond), Wt: N x Kp bf16 (k zero-padded)
// grid = (M/128, ceil(N/64)), 256 threads (4 waves, 2x2), tile 128x64, BK=32.
template <int EP, typename TRes, typename TOut>
__global__ __launch_bounds__(256) void gemm_mfma(
    const bf16* __restrict__ A, const bf16* __restrict__ Wt,
    const float* __restrict__ bias, const TRes* __restrict__ res,
    TOut* __restrict__ out, int N, int KlimA, int lda, int Kp, int ldout, int ldres)
{
  __shared__ __align__(16) short Al[128 * 32];
  __shared__ __align__(16) short Bl[64 * 32];
  int tid = threadIdx.x;
  int wave = tid >> 6, lane = tid & 63;
  int wy = wave >> 1, wx = wave & 1;
  int m0 = blockIdx.x * 128, n0 = blockIdx.y * 64;

  f32x4 acc[4][2] = {};

  int ar = tid >> 2;            // 0..63 (chunk row)
  int ac = (tid & 3) * 8;       // k-offset of this 16B chunk
  int brow = n0 + ar;           // Wt row (n index)
  int browc = (brow < N) ? brow : (N - 1);
  bool bvalid = (brow < N);
  const uint4* ga0 = (const uint4*)(A + (size_t)(m0 + ar) * lda + ac);
  const uint4* ga1 = (const uint4*)(A + (size_t)(m0 + 64 + ar) * lda + ac);
  const uint4* gb  = (const uint4*)(Wt + (size_t)browc * Kp + ac);

  int fm = lane & 15, quad = lane >> 4;
  const short* afp = &Al[(wy * 64 + fm) * 32 + quad * 8];
  const short* bfp = &Bl[(wx * 32 + fm) * 32 + quad * 8];

  for (int k0 = 0; k0 < Kp; k0 += 32) {
    bool avalid = (k0 + ac) < KlimA;   // chunks are 8-elem granular; KlimA % 8 == 0
    uint4 za = avalid ? ga0[k0 / 8] : make_uint4(0, 0, 0, 0);
    uint4 zb = avalid ? ga1[k0 / 8] : make_uint4(0, 0, 0, 0);
    uint4 zc = bvalid ? gb[k0 / 8]  : make_uint4(0, 0, 0, 0);
    __syncthreads();                   // previous iteration's ds_reads complete
    *(uint4*)&Al[tid * 8]        = za;
    *(uint4*)&Al[2048 + tid * 8] = zb;
    *(uint4*)&Bl[tid * 8]        = zc;
    __syncthreads();

    bf16x8 af0 = *(const bf16x8*)(afp);
    bf16x8 af1 = *(const bf16x8*)(afp + 16 * 32);
    bf16x8 af2 = *(const bf16x8*)(afp + 32 * 32);
    bf16x8 af3 = *(const bf16x8*)(afp + 48 * 32);
    bf16x8 bf0 = *(const bf16x8*)(bfp);
    bf16x8 bf1 = *(const bf16x8*)(bfp + 16 * 32);

    acc[0][0] = __builtin_amdgcn_mfma_f32_16x16x32_bf16(af0, bf0, acc[0][0], 0, 0, 0);
    acc[0][1] = __builtin_amdgcn_mfma_f32_16x16x32_bf16(af0, bf1, acc[0][1], 0, 0, 0);
    acc[1][0] = __builtin_amdgcn_mfma_f32_16x16x32_bf16(af1, bf0, acc[1][0], 0, 0, 0);
    acc[1][1] = __builtin_amdgcn_mfma_f32_16x16x32_bf16(af1, bf1, acc[1][1], 0, 0, 0);
    acc[2][0] = __builtin_amdgcn_mfma_f32_16x16x32_bf16(af2, bf0, acc[2][0], 0, 0, 0);
    acc[2][1] = __builtin_amdgcn_mfma_f32_16x16x32_bf16(af2, bf1, acc[2][1], 0, 0, 0);
    acc[3][0] = __builtin_amdgcn_mfma_f32_16x16x32_bf16(af3, bf0, acc[3][0], 0, 0, 0);
    acc[3][1] = __builtin_amdgcn_mfma_f32_16x16x32_bf16(af3, bf1, acc[3][1], 0, 0, 0);
  }

  // epilogue: C/D layout col = lane&15, row = quad*4 + reg   [m89/m91 verified]
  #pragma unroll
  for (int nt = 0; nt < 2; nt++) {
    int col = n0 + wx * 32 + nt * 16 + fm;
    if (col >= N) continue;
    float bv = bias[col];
    #pragma unroll
    for (int mt = 0; mt < 4; mt++) {
      int row0 = m0 + wy * 64 + mt * 16 + quad * 4;
      #pragma unroll
      for (int r = 0; r < 4; r++) {
        int row = row0 + r;
        float v = acc[mt][nt][r] + bv;
        if constexpr (EP == 1) v += toF(res[(size_t)row * ldres + col]);
        if constexpr (EP == 2) v = 0.5f * v * (1.f + erff(v * 0.70710678118654752f));
        stF(&out[(size_t)row * ldout + col], v);
      }
    }
  }
}

// ---------------- attention: one block per (window, head) -------------------------------
// q,k: bf16 stride 180; v: bf16 stride 720; xw out bf16 stride 720
__global__ __launch_bounds__(256) void attn_kernel(
    const bf16* __restrict__ q, const bf16* __restrict__ k, const bf16* __restrict__ v,
    const int* __restrict__ rpi, const float* __restrict__ rpb, bf16* __restrict__ xw)
{
  __shared__ float q_lds[64 * 30];
  __shared__ float s_lds[64 * 145];          // +1 pad: kills P-read bank conflicts
  __shared__ float rowinv[64];
  __shared__ __align__(16) unsigned short kv_lds[72 * 120];  // K patch (4320) then V chunks
  const float scale = 0.18257418583505536f;  // 30^-0.5
  int blk = blockIdx.x;
  int hh = blk % 6; int wid = blk / 6;
  int wj = wid & 15; int wi = (wid >> 4) & 15; int b = wid >> 8;
  int tid = threadIdx.x;
  const unsigned short* ku = (const unsigned short*)k;
  const unsigned short* vu = (const unsigned short*)v;

  // stage q (pre-scaled fp32) and K patch (bf16 bits, zeros for halo)
  for (int e = tid; e < 1920; e += 256) {
    int r = e / 30, dd = e % 30;
    int gy = wi * 8 + (r >> 3), gx = wj * 8 + (r & 7);
    q_lds[e] = scale * b2f(q[((size_t)b * 16384 + (size_t)gy * 128 + gx) * 180 + hh * 30 + dd]);
  }
  for (int e = tid; e < 4320; e += 256) {
    int kk = e / 30, dd = e % 30;
    int ky = kk / 12, kx = kk % 12;
    int gy = wi * 8 - 4 + ky, gx = wj * 8 - 4 + kx;
    unsigned short val = 0;
    if (gy >= 0 && gy < 128 && gx >= 0 && gx < 128)
      val = ku[((size_t)b * 16384 + (size_t)gy * 128 + gx) * 180 + hh * 30 + dd];
    kv_lds[e] = val;
  }
  __syncthreads();

  // scores: thread (r, dg) computes kk = dg, dg+4, ... (zero K rows -> bias-only, matches pad)
  {
    int r = tid >> 2, dg = tid & 3;
    float qreg[30];
    const float* qp = q_lds + r * 30;
    #pragma unroll
    for (int i = 0; i < 30; i++) qreg[i] = qp[i];
    for (int kk = dg; kk < 144; kk += 4) {
      const unsigned int* kp = (const unsigned int*)&kv_lds[kk * 30];
      float acc = 0.f;
      #pragma unroll
      for (int i = 0; i < 15; i++) {
        unsigned int u = kp[i];
        acc = fmaf(qreg[2 * i],     __uint_as_float(u << 16), acc);
        acc = fmaf(qreg[2 * i + 1], __uint_as_float(u & 0xffff0000u), acc);
      }
      acc += rpb[rpi[r * 144 + kk] * 6 + hh];
      s_lds[r * 145 + kk] = acc;
    }
  }
  __syncthreads();

  // softmax per row
  int wave = tid >> 6, lane = tid & 63;
  for (int r = wave * 16; r < wave * 16 + 16; r++) {
    float* row = s_lds + r * 145;
    float x0 = row[lane];
    float x1 = row[lane + 64];
    float x2 = (lane < 16) ? row[lane + 128] : -1e30f;
    float m = fmaxf(fmaxf(x0, x1), x2);
    #pragma unroll
    for (int sh = 32; sh; sh >>= 1) m = fmaxf(m, __shfl_xor(m, sh));
    float e0 = expf(x0 - m);
    float e1 = expf(x1 - m);
    float e2 = (lane < 16) ? expf(x2 - m) : 0.f;
    row[lane] = e0;
    row[lane + 64] = e1;
    if (lane < 16) row[lane + 128] = e2;
    float sum = e0 + e1 + e2;
    #pragma unroll
    for (int sh = 32; sh; sh >>= 1) sum += __shfl_xor(sum, sh);
    if (lane == 0) rowinv[r] = 1.f / sum;
  }
  __syncthreads();

  // PV: thread (r, dg) accumulates 30 channels dd = dg*30 .. +30
  int r = tid >> 2, dg = tid & 3;
  float acc2[30];
  #pragma unroll
  for (int i = 0; i < 30; i++) acc2[i] = 0.f;
  for (int ck = 0; ck < 2; ck++) {
    for (int e = tid; e < 8640; e += 256) {
      int kl = e / 120, dd = e % 120;
      int kkg = ck * 72 + kl;
      int ky = kkg / 12, kx = kkg % 12;
      int gy = wi * 8 - 4 + ky, gx = wj * 8 - 4 + kx;
      unsigned short val = 0;
      if (gy >= 0 && gy < 128 && gx >= 0 && gx < 128)
        val = vu[((size_t)b * 16384 + (size_t)gy * 128 + gx) * 720 + hh * 120 + dd];
      kv_lds[e] = val;
    }
    __syncthreads();
    const float* prow = s_lds + r * 145 + ck * 72;
    for (int kl = 0; kl < 72; kl++) {
      float p = prow[kl];
      const unsigned int* vp = (const unsigned int*)&kv_lds[kl * 120 + dg * 30];
      #pragma unroll
      for (int i = 0; i < 15; i++) {
        unsigned int u = vp[i];
        acc2[2 * i]     = fmaf(p, __uint_as_float(u << 16), acc2[2 * i]);
        acc2[2 * i + 1] = fmaf(p, __uint_as_float(u & 0xffff0000u), acc2[2 * i + 1]);
      }
    }
    __syncthreads();
  }
  {
    float rinv = rowinv[r];
    int gy = wi * 8 + (r >> 3), gx = wj * 8 + (r & 7);
    bf16* op = xw + ((size_t)b * 16384 + (size_t)gy * 128 + gx) * 720 + hh * 120 + dg * 30;
    #pragma unroll
    for (int i = 0; i < 30; i++) op[i] = f2b(acc2[i] * rinv);
  }
}

// ---------------- IDWT: xw bf16 (.,720) -> xr bf16 stride 192 (zero-padded 180..191) ----
__global__ __launch_bounds__(256) void idwt_kernel(
    const bf16* __restrict__ xw, bf16* __restrict__ xr)
{
  size_t gid = (size_t)blockIdx.x * 256 + threadIdx.x;
  if (gid >= 25165824ull) return;   // 131072 * 192
  int c = (int)(gid % 192); size_t tok = gid / 192;
  if (c >= 180) { xr[gid] = f2b(0.f); return; }
  int x2 = (int)(tok % 256); size_t rest2 = tok / 256;
  int y2 = (int)(rest2 % 256); int b = (int)(rest2 / 256);
  int i = y2 >> 1, j = x2 >> 1, py = y2 & 1, px = x2 & 1;
  const bf16* p = xw + ((size_t)b * 16384 + (size_t)i * 128 + j) * 720 + c;
  float ll = b2f(p[0]), lh = b2f(p[180]), hl = b2f(p[360]), hh = b2f(p[540]);
  float r;
  if (py == 0 && px == 0)      r = ll - lh - hl + hh;
  else if (py == 0)            r = ll - lh + hl - hh;
  else if (px == 0)            r = ll + lh - hl - hh;
  else                         r = ll + lh + hl + hh;
  xr[gid] = f2b(r * 0.5f);
}

extern "C" void kernel_launch(void* const* d_in, const int* in_sizes, int n_in,
                              void* d_out, int out_size, void* d_ws, size_t ws_size,
                              hipStream_t stream) {
  (void)in_sizes; (void)n_in; (void)out_size; (void)ws_size;
  const float* x      = (const float*)d_in[0];
  const int*   rpi    = (const int*)  d_in[2];
  const float* n1w    = (const float*)d_in[5];
  const float* n1b    = (const float*)d_in[6];
  const float* q_w    = (const float*)d_in[9];
  const float* q_b    = (const float*)d_in[10];
  const float* k_w    = (const float*)d_in[11];
  const float* k_b    = (const float*)d_in[12];
  const float* v_w    = (const float*)d_in[13];
  const float* v_b    = (const float*)d_in[14];
  const float* rpb    = (const float*)d_in[15];
  const float* proj_w = (const float*)d_in[16];
  const float* proj_b = (const float*)d_in[17];
  const float* n2w    = (const float*)d_in[18];
  const float* n2b    = (const float*)d_in[19];
  const float* fc1_w  = (const float*)d_in[20];
  const float* fc1_b  = (const float*)d_in[21];
  const float* fc2_w  = (const float*)d_in[22];
  const float* fc2_b  = (const float*)d_in[23];
  float* out = (float*)d_out;

  // ---- workspace layout (bf16 elements), ~261.5 MB ----
  bf16* xd  = (bf16*)d_ws;                  // 32768 x 720 = 23,592,960   (reused: xw, then yb)
  bf16* qb  = xd + 23592960;                // 32768 x 180 =  5,898,240
  bf16* kb  = qb + 5898240;                 //                5,898,240
  bf16* vb  = kb + 5898240;                 // 32768 x 720 = 23,592,960
  bf16* x1  = vb + 23592960;                // 131072 x 180 = 23,592,960
  bf16* hb  = x1 + 23592960;                // 131072 x 360 = 47,185,920
  bf16* wts = hb + 47185920;                //                  967,680
  bf16* qwt  = wts;                         // 180 x 736
  bf16* kwt  = qwt + 132480;                // 180 x 736
  bf16* vwt  = kwt + 132480;                // 720 x 736
  bf16* pwt  = vwt + 529920;                // 180 x 192
  bf16* f1wt = pwt + 34560;                 // 360 x 192
  bf16* f2wt = f1wt + 69120;                // 180 x 384
  bf16* xw = xd;                            // after attn (xd dead)
  bf16* xr = qb + 10223616;                 // 131072 x 192 = 25,165,824 (tail of q/k/v region)
  bf16* yb = xd;                            // 131072 x 192 (xd+spill into dead qb head)

  // weight repack (runs every call; ~1M elems total)
  convert_wt_kernel<<<518,  256, 0, stream>>>(q_w,    qwt,  720, 180, 736);
  convert_wt_kernel<<<518,  256, 0, stream>>>(k_w,    kwt,  720, 180, 736);
  convert_wt_kernel<<<2071, 256, 0, stream>>>(v_w,    vwt,  720, 720, 736);
  convert_wt_kernel<<<135,  256, 0, stream>>>(proj_w, pwt,  180, 180, 192);
  convert_wt_kernel<<<270,  256, 0, stream>>>(fc1_w,  f1wt, 180, 360, 192);
  convert_wt_kernel<<<270,  256, 0, stream>>>(fc2_w,  f2wt, 360, 180, 384);

  ln_dwt_kernel<<<32768, 256, 0, stream>>>(x, n1w, n1b, xd);
  gemm_mfma<0, float, bf16><<<dim3(256, 3),  256, 0, stream>>>(xd, qwt, q_b, nullptr, qb, 180, 720, 720, 736, 180, 0);
  gemm_mfma<0, float, bf16><<<dim3(256, 3),  256, 0, stream>>>(xd, kwt, k_b, nullptr, kb, 180, 720, 720, 736, 180, 0);
  gemm_mfma<0, float, bf16><<<dim3(256, 12), 256, 0, stream>>>(xd, vwt, v_b, nullptr, vb, 720, 720, 720, 736, 720, 0);
  attn_kernel<<<3072, 256, 0, stream>>>(qb, kb, vb, rpi, rpb, xw);
  idwt_kernel<<<98304, 256, 0, stream>>>(xw, xr);
  gemm_mfma<1, float, bf16><<<dim3(1024, 3), 256, 0, stream>>>(xr, pwt, proj_b, x, x1, 180, 192, 192, 192, 180, 180);
  ln_kernel<<<32768, 256, 0, stream>>>(x1, n2w, n2b, yb);
  gemm_mfma<2, float, bf16><<<dim3(1024, 6), 256, 0, stream>>>(yb, f1wt, fc1_b, nullptr, hb, 360, 192, 192, 192, 360, 0);
  gemm_mfma<1, bf16, float><<<dim3(1024, 3), 256, 0, stream>>>(hb, f2wt, fc2_b, x1, out, 180, 360, 360, 384, 180, 180);
}

// Round 4
// 943.418 us; speedup vs baseline: 3.4137x; 1.2375x over previous
//
#include <hip/hip_runtime.h>
#include <hip/hip_bf16.h>
#include <stdint.h>

using bf16 = __hip_bfloat16;
typedef __attribute__((ext_vector_type(8))) short bf16x8;
typedef __attribute__((ext_vector_type(4))) float f32x4;

static __device__ __forceinline__ float b2f(bf16 v) { return __bfloat162float(v); }
static __device__ __forceinline__ bf16  f2b(float v) { return __float2bfloat16(v); }
static __device__ __forceinline__ float toF(float v) { return v; }
static __device__ __forceinline__ float toF(bf16 v)  { return __bfloat162float(v); }
static __device__ __forceinline__ void stF(float* p, float v) { *p = v; }
static __device__ __forceinline__ void stF(bf16* p,  float v) { *p = f2b(v); }

// ---------------- weight convert: w[k][n] fp32 -> wt[n][k] bf16, k zero-padded to Kp ----
__global__ __launch_bounds__(256) void convert_wt_kernel(
    const float* __restrict__ w, bf16* __restrict__ wt, int K, int N, int Kp)
{
  int idx = blockIdx.x * 256 + threadIdx.x;
  if (idx >= N * Kp) return;
  int n = idx / Kp, k = idx % Kp;
  float v = (k < K) ? w[(size_t)k * N + n] : 0.f;
  wt[idx] = f2b(v);
}

// ---------------- bias precompute: bias_f[hh][r][kk] = rpb[rpi[r,kk]*6+hh] --------------
__global__ __launch_bounds__(256) void bias_pre_kernel(
    const int* __restrict__ rpi, const float* __restrict__ rpb, float* __restrict__ bias_f)
{
  int e = blockIdx.x * 256 + threadIdx.x;
  if (e >= 6 * 64 * 144) return;
  int hh = e / 9216, rk = e % 9216;
  bias_f[e] = rpb[rpi[rk] * 6 + hh];
}

// ---------------- LN1 + DWT: x fp32 (2,256,256,180) -> xd bf16 (2,128,128,720) ----------
__global__ __launch_bounds__(256) void ln_dwt_kernel(
    const float* __restrict__ x, const float* __restrict__ w, const float* __restrict__ bia,
    bf16* __restrict__ xd)
{
  __shared__ float nrm[4][180];
  int blk = blockIdx.x;
  int j = blk & 127; int i = (blk >> 7) & 127; int b = blk >> 14;
  int wave = threadIdx.x >> 6, lane = threadIdx.x & 63;
  int ty = wave >> 1, tx = wave & 1;
  size_t tok = (size_t)b * 65536 + (size_t)(2 * i + ty) * 256 + (size_t)(2 * j + tx);
  const float* xp = x + tok * 180;
  float v0 = xp[lane];
  float v1 = xp[lane + 64];
  float v2 = (lane < 52) ? xp[lane + 128] : 0.f;
  float s = v0 + v1 + v2, ss = v0 * v0 + v1 * v1 + v2 * v2;
  #pragma unroll
  for (int m = 32; m; m >>= 1) { s += __shfl_xor(s, m); ss += __shfl_xor(ss, m); }
  float mu = s * (1.f / 180.f);
  float rstd = rsqrtf(ss * (1.f / 180.f) - mu * mu + 1e-5f);
  nrm[wave][lane]      = (v0 - mu) * rstd * w[lane]      + bia[lane];
  nrm[wave][lane + 64] = (v1 - mu) * rstd * w[lane + 64] + bia[lane + 64];
  if (lane < 52)
    nrm[wave][lane + 128] = (v2 - mu) * rstd * w[lane + 128] + bia[lane + 128];
  __syncthreads();
  bf16* op = xd + (size_t)blk * 720;
  for (int o = threadIdx.x; o < 720; o += 256) {
    int g = o / 180, c = o % 180;
    float a = nrm[0][c], bb = nrm[1][c], cc = nrm[2][c], dd = nrm[3][c];
    float r = (g == 0) ? (a + bb + cc + dd)
            : (g == 1) ? (-a - bb + cc + dd)
            : (g == 2) ? (-a + bb - cc + dd)
                       : (a - bb - cc + dd);
    op[o] = f2b(r * 0.5f);
  }
}

// ---------------- plain LN: x1 bf16 (131072,180) -> y bf16 stride 192 (zero-padded) -----
__global__ __launch_bounds__(256) void ln_kernel(
    const bf16* __restrict__ x, const float* __restrict__ w, const float* __restrict__ bia,
    bf16* __restrict__ y)
{
  int wave = threadIdx.x >> 6, lane = threadIdx.x & 63;
  size_t tok = (size_t)blockIdx.x * 4 + wave;
  const bf16* xp = x + tok * 180;
  float v0 = b2f(xp[lane]);
  float v1 = b2f(xp[lane + 64]);
  float v2 = (lane < 52) ? b2f(xp[lane + 128]) : 0.f;
  float s = v0 + v1 + v2, ss = v0 * v0 + v1 * v1 + v2 * v2;
  #pragma unroll
  for (int m = 32; m; m >>= 1) { s += __shfl_xor(s, m); ss += __shfl_xor(ss, m); }
  float mu = s * (1.f / 180.f);
  float rstd = rsqrtf(ss * (1.f / 180.f) - mu * mu + 1e-5f);
  bf16* yp = y + tok * 192;
  yp[lane]      = f2b((v0 - mu) * rstd * w[lane]      + bia[lane]);
  yp[lane + 64] = f2b((v1 - mu) * rstd * w[lane + 64] + bia[lane + 64]);
  if (lane < 52)
    yp[lane + 128] = f2b((v2 - mu) * rstd * w[lane + 128] + bia[lane + 128]);
  else
    yp[lane + 128] = f2b(0.f);
}

// ---------------- MFMA GEMM: out = ep(A@Wt^T + bias [, res]) ----------------------------
template <int EP, typename TRes, typename TOut>
__global__ __launch_bounds__(256) void gemm_mfma(
    const bf16* __restrict__ A, const bf16* __restrict__ Wt,
    const float* __restrict__ bias, const TRes* __restrict__ res,
    TOut* __restrict__ out, int N, int KlimA, int lda, int Kp, int ldout, int ldres)
{
  __shared__ __align__(16) short Al[128 * 32];
  __shared__ __align__(16) short Bl[64 * 32];
  int tid = threadIdx.x;
  int wave = tid >> 6, lane = tid & 63;
  int wy = wave >> 1, wx = wave & 1;
  int m0 = blockIdx.x * 128, n0 = blockIdx.y * 64;

  f32x4 acc[4][2] = {};

  int ar = tid >> 2;
  int ac = (tid & 3) * 8;
  int brow = n0 + ar;
  int browc = (brow < N) ? brow : (N - 1);
  bool bvalid = (brow < N);
  const uint4* ga0 = (const uint4*)(A + (size_t)(m0 + ar) * lda + ac);
  const uint4* ga1 = (const uint4*)(A + (size_t)(m0 + 64 + ar) * lda + ac);
  const uint4* gb  = (const uint4*)(Wt + (size_t)browc * Kp + ac);

  int fm = lane & 15, quad = lane >> 4;
  const short* afp = &Al[(wy * 64 + fm) * 32 + quad * 8];
  const short* bfp = &Bl[(wx * 32 + fm) * 32 + quad * 8];

  for (int k0 = 0; k0 < Kp; k0 += 32) {
    bool avalid = (k0 + ac) < KlimA;
    uint4 za = avalid ? ga0[k0 / 8] : make_uint4(0, 0, 0, 0);
    uint4 zb = avalid ? ga1[k0 / 8] : make_uint4(0, 0, 0, 0);
    uint4 zc = bvalid ? gb[k0 / 8]  : make_uint4(0, 0, 0, 0);
    __syncthreads();
    *(uint4*)&Al[tid * 8]        = za;
    *(uint4*)&Al[2048 + tid * 8] = zb;
    *(uint4*)&Bl[tid * 8]        = zc;
    __syncthreads();

    bf16x8 af0 = *(const bf16x8*)(afp);
    bf16x8 af1 = *(const bf16x8*)(afp + 16 * 32);
    bf16x8 af2 = *(const bf16x8*)(afp + 32 * 32);
    bf16x8 af3 = *(const bf16x8*)(afp + 48 * 32);
    bf16x8 bf0 = *(const bf16x8*)(bfp);
    bf16x8 bf1 = *(const bf16x8*)(bfp + 16 * 32);

    acc[0][0] = __builtin_amdgcn_mfma_f32_16x16x32_bf16(af0, bf0, acc[0][0], 0, 0, 0);
    acc[0][1] = __builtin_amdgcn_mfma_f32_16x16x32_bf16(af0, bf1, acc[0][1], 0, 0, 0);
    acc[1][0] = __builtin_amdgcn_mfma_f32_16x16x32_bf16(af1, bf0, acc[1][0], 0, 0, 0);
    acc[1][1] = __builtin_amdgcn_mfma_f32_16x16x32_bf16(af1, bf1, acc[1][1], 0, 0, 0);
    acc[2][0] = __builtin_amdgcn_mfma_f32_16x16x32_bf16(af2, bf0, acc[2][0], 0, 0, 0);
    acc[2][1] = __builtin_amdgcn_mfma_f32_16x16x32_bf16(af2, bf1, acc[2][1], 0, 0, 0);
    acc[3][0] = __builtin_amdgcn_mfma_f32_16x16x32_bf16(af3, bf0, acc[3][0], 0, 0, 0);
    acc[3][1] = __builtin_amdgcn_mfma_f32_16x16x32_bf16(af3, bf1, acc[3][1], 0, 0, 0);
  }

  #pragma unroll
  for (int nt = 0; nt < 2; nt++) {
    int col = n0 + wx * 32 + nt * 16 + fm;
    if (col >= N) continue;
    float bv = bias[col];
    #pragma unroll
    for (int mt = 0; mt < 4; mt++) {
      int row0 = m0 + wy * 64 + mt * 16 + quad * 4;
      #pragma unroll
      for (int r = 0; r < 4; r++) {
        int row = row0 + r;
        float v = acc[mt][nt][r] + bv;
        if constexpr (EP == 1) v += toF(res[(size_t)row * ldres + col]);
        if constexpr (EP == 2) v = 0.5f * v * (1.f + erff(v * 0.70710678118654752f));
        stF(&out[(size_t)row * ldout + col], v);
      }
    }
  }
}

// ---------------- MFMA attention: one block per (window, head) --------------------------
// q,k: bf16 stride 180; v: bf16 stride 720; xw out bf16 stride 720; bias_f: [6][64][144]
__global__ __launch_bounds__(256) void attn_kernel(
    const bf16* __restrict__ q, const bf16* __restrict__ k, const bf16* __restrict__ v,
    const float* __restrict__ bias_f, bf16* __restrict__ xw)
{
  __shared__ __align__(16) short regA[64 * 168];    // Q[64][40] + K[144][40]; later P[64][168]
  __shared__ __align__(16) short regB[128 * 168];   // Vt[128][168] (n=dd, k=kk), zero-padded
  const float scale = 0.18257418583505536f;  // 30^-0.5
  int blk = blockIdx.x;
  int hh = blk % 6; int wid = blk / 6;
  int wj = wid & 15; int wi = (wid >> 4) & 15; int b = wid >> 8;
  int tid = threadIdx.x;
  int wave = tid >> 6, lane = tid & 63;
  int fm = lane & 15, quad = lane >> 4;
  const unsigned short* qu = (const unsigned short*)q;
  const unsigned short* ku = (const unsigned short*)k;
  const unsigned short* vu = (const unsigned short*)v;

  // ---- phase 1: zero Vt; stage Q [64][40] and K [144][40] (bf16 bits, zero halo/pad) ----
  for (int e = tid; e < 10752; e += 256) *(unsigned int*)&regB[e * 2] = 0u;
  for (int e = tid; e < 1280; e += 256) {            // Q: 64 rows x 20 uints
    int r = e / 20, up = e % 20;
    unsigned int val = 0;
    if (up < 15) {
      int gy = wi * 8 + (r >> 3), gx = wj * 8 + (r & 7);
      const unsigned short* p = qu + ((size_t)b * 16384 + (size_t)gy * 128 + gx) * 180 + hh * 30 + up * 2;
      val = (unsigned int)p[0] | ((unsigned int)p[1] << 16);
    }
    *(unsigned int*)&regA[r * 40 + up * 2] = val;
  }
  for (int e = tid; e < 2880; e += 256) {            // K: 144 rows x 20 uints
    int kk = e / 20, up = e % 20;
    unsigned int val = 0;
    if (up < 15) {
      int ky = kk / 12, kx = kk % 12;
      int gy = wi * 8 - 4 + ky, gx = wj * 8 - 4 + kx;
      if (gy >= 0 && gy < 128 && gx >= 0 && gx < 128) {
        const unsigned short* p = ku + ((size_t)b * 16384 + (size_t)gy * 128 + gx) * 180 + hh * 30 + up * 2;
        val = (unsigned int)p[0] | ((unsigned int)p[1] << 16);
      }
    }
    *(unsigned int*)&regA[2560 + kk * 40 + up * 2] = val;
  }
  __syncthreads();

  // ---- phase 2: scatter V -> Vt; QK MFMA; softmax in registers ----
  for (int e = tid; e < 17280; e += 256) {           // V: 144 kv-rows x 120 channels
    int kk = e / 120, dd = e % 120;
    int ky = kk / 12, kx = kk % 12;
    int gy = wi * 8 - 4 + ky, gx = wj * 8 - 4 + kx;
    if (gy >= 0 && gy < 128 && gx >= 0 && gx < 128)
      regB[dd * 168 + kk] =
          (short)vu[((size_t)b * 16384 + (size_t)gy * 128 + gx) * 720 + hh * 120 + dd];
  }

  f32x4 sacc[9] = {};
  {
    bf16x8 afrag = *(const bf16x8*)&regA[(wave * 16 + fm) * 40 + quad * 8];
    #pragma unroll
    for (int nt = 0; nt < 9; nt++) {
      bf16x8 bfrag = *(const bf16x8*)&regA[2560 + (nt * 16 + fm) * 40 + quad * 8];
      sacc[nt] = __builtin_amdgcn_mfma_f32_16x16x32_bf16(afrag, bfrag, sacc[nt], 0, 0, 0);
    }
  }
  float sv[9][4];
  const float* bias_g = bias_f + hh * 9216;
  {
    #pragma unroll
    for (int r = 0; r < 4; r++) {
      int row = wave * 16 + quad * 4 + r;
      #pragma unroll
      for (int nt = 0; nt < 9; nt++)
        sv[nt][r] = sacc[nt][r] * scale + bias_g[row * 144 + nt * 16 + fm];
    }
    float mr[4], sr[4];
    #pragma unroll
    for (int r = 0; r < 4; r++) {
      float m = sv[0][r];
      #pragma unroll
      for (int nt = 1; nt < 9; nt++) m = fmaxf(m, sv[nt][r]);
      #pragma unroll
      for (int sh = 1; sh < 16; sh <<= 1) m = fmaxf(m, __shfl_xor(m, sh));
      mr[r] = m;
    }
    #pragma unroll
    for (int r = 0; r < 4; r++) {
      float s = 0.f;
      #pragma unroll
      for (int nt = 0; nt < 9; nt++) { sv[nt][r] = expf(sv[nt][r] - mr[r]); s += sv[nt][r]; }
      #pragma unroll
      for (int sh = 1; sh < 16; sh <<= 1) s += __shfl_xor(s, sh);
      sr[r] = 1.f / s;
    }
    #pragma unroll
    for (int r = 0; r < 4; r++)
      #pragma unroll
      for (int nt = 0; nt < 9; nt++) sv[nt][r] *= sr[r];
  }
  __syncthreads();  // all waves done reading Q/K; Vt scatter complete

  // ---- phase 3: write normalized P (bf16) into regA as [64][168]; zero pad cols ----
  #pragma unroll
  for (int r = 0; r < 4; r++) {
    int row = wave * 16 + quad * 4 + r;
    #pragma unroll
    for (int nt = 0; nt < 9; nt++)
      regA[row * 168 + nt * 16 + fm] = (short)__bfloat16_as_ushort(f2b(sv[nt][r]));
  }
  for (int e = tid; e < 768; e += 256) {             // zero P cols 144..167
    int row = e / 12, cp = e % 12;
    *(unsigned int*)&regA[row * 168 + 144 + cp * 2] = 0u;
  }
  __syncthreads();

  // ---- phase 4: O = P @ Vt^T  (M=64, N=128, K=160) ----
  f32x4 oacc[8] = {};
  #pragma unroll
  for (int ks = 0; ks < 5; ks++) {
    bf16x8 pf = *(const bf16x8*)&regA[(wave * 16 + fm) * 168 + ks * 32 + quad * 8];
    #pragma unroll
    for (int nt = 0; nt < 8; nt++) {
      bf16x8 vf = *(const bf16x8*)&regB[(nt * 16 + fm) * 168 + ks * 32 + quad * 8];
      oacc[nt] = __builtin_amdgcn_mfma_f32_16x16x32_bf16(pf, vf, oacc[nt], 0, 0, 0);
    }
  }
  #pragma unroll
  for (int nt = 0; nt < 8; nt++) {
    int col = nt * 16 + fm;
    if (col >= 120) continue;
    #pragma unroll
    for (int r = 0; r < 4; r++) {
      int row = wave * 16 + quad * 4 + r;
      int gy = wi * 8 + (row >> 3), gx = wj * 8 + (row & 7);
      xw[((size_t)b * 16384 + (size_t)gy * 128 + gx) * 720 + hh * 120 + col] = f2b(oacc[nt][r]);
    }
  }
}

// ---------------- IDWT: xw bf16 (.,720) -> xr bf16 stride 192 (zero-padded 180..191) ----
__global__ __launch_bounds__(256) void idwt_kernel(
    const bf16* __restrict__ xw, bf16* __restrict__ xr)
{
  size_t gid = (size_t)blockIdx.x * 256 + threadIdx.x;
  if (gid >= 25165824ull) return;
  int c = (int)(gid % 192); size_t tok = gid / 192;
  if (c >= 180) { xr[gid] = f2b(0.f); return; }
  int x2 = (int)(tok % 256); size_t rest2 = tok / 256;
  int y2 = (int)(rest2 % 256); int b = (int)(rest2 / 256);
  int i = y2 >> 1, j = x2 >> 1, py = y2 & 1, px = x2 & 1;
  const bf16* p = xw + ((size_t)b * 16384 + (size_t)i * 128 + j) * 720 + c;
  float ll = b2f(p[0]), lh = b2f(p[180]), hl = b2f(p[360]), hh = b2f(p[540]);
  float r;
  if (py == 0 && px == 0)      r = ll - lh - hl + hh;
  else if (py == 0)            r = ll - lh + hl - hh;
  else if (px == 0)            r = ll + lh - hl - hh;
  else                         r = ll + lh + hl + hh;
  xr[gid] = f2b(r * 0.5f);
}

extern "C" void kernel_launch(void* const* d_in, const int* in_sizes, int n_in,
                              void* d_out, int out_size, void* d_ws, size_t ws_size,
                              hipStream_t stream) {
  (void)in_sizes; (void)n_in; (void)out_size; (void)ws_size;
  const float* x      = (const float*)d_in[0];
  const int*   rpi    = (const int*)  d_in[2];
  const float* n1w    = (const float*)d_in[5];
  const float* n1b    = (const float*)d_in[6];
  const float* q_w    = (const float*)d_in[9];
  const float* q_b    = (const float*)d_in[10];
  const float* k_w    = (const float*)d_in[11];
  const float* k_b    = (const float*)d_in[12];
  const float* v_w    = (const float*)d_in[13];
  const float* v_b    = (const float*)d_in[14];
  const float* rpb    = (const float*)d_in[15];
  const float* proj_w = (const float*)d_in[16];
  const float* proj_b = (const float*)d_in[17];
  const float* n2w    = (const float*)d_in[18];
  const float* n2b    = (const float*)d_in[19];
  const float* fc1_w  = (const float*)d_in[20];
  const float* fc1_b  = (const float*)d_in[21];
  const float* fc2_w  = (const float*)d_in[22];
  const float* fc2_b  = (const float*)d_in[23];
  float* out = (float*)d_out;

  // ---- workspace layout (bf16 elements) ----
  bf16* xd  = (bf16*)d_ws;                  // 32768 x 720   (reused: xw, then yb)
  bf16* qb  = xd + 23592960;                // 32768 x 180
  bf16* kb  = qb + 5898240;                 // 32768 x 180
  bf16* vb  = kb + 5898240;                 // 32768 x 720
  bf16* x1  = vb + 23592960;                // 131072 x 180
  bf16* hb  = x1 + 23592960;                // 131072 x 360
  bf16* wts = hb + 47185920;
  bf16* qwt  = wts;                         // 180 x 736
  bf16* kwt  = qwt + 132480;                // 180 x 736
  bf16* vwt  = kwt + 132480;                // 720 x 736
  bf16* pwt  = vwt + 529920;                // 180 x 192
  bf16* f1wt = pwt + 34560;                 // 360 x 192
  bf16* f2wt = f1wt + 69120;                // 180 x 384
  float* bias_f = (float*)(f2wt + 69120);   // 6 x 64 x 144 fp32
  bf16* xw = xd;
  bf16* xr = qb + 10223616;                 // 131072 x 192 (tail of q/k/v region)
  bf16* yb = xd;

  convert_wt_kernel<<<518,  256, 0, stream>>>(q_w,    qwt,  720, 180, 736);
  convert_wt_kernel<<<518,  256, 0, stream>>>(k_w,    kwt,  720, 180, 736);
  convert_wt_kernel<<<2071, 256, 0, stream>>>(v_w,    vwt,  720, 720, 736);
  convert_wt_kernel<<<135,  256, 0, stream>>>(proj_w, pwt,  180, 180, 192);
  convert_wt_kernel<<<270,  256, 0, stream>>>(fc1_w,  f1wt, 180, 360, 192);
  convert_wt_kernel<<<270,  256, 0, stream>>>(fc2_w,  f2wt, 360, 180, 384);
  bias_pre_kernel<<<216, 256, 0, stream>>>(rpi, rpb, bias_f);

  ln_dwt_kernel<<<32768, 256, 0, stream>>>(x, n1w, n1b, xd);
  gemm_mfma<0, float, bf16><<<dim3(256, 3),  256, 0, stream>>>(xd, qwt, q_b, nullptr, qb, 180, 720, 720, 736, 180, 0);
  gemm_mfma<0, float, bf16><<<dim3(256, 3),  256, 0, stream>>>(xd, kwt, k_b, nullptr, kb, 180, 720, 720, 736, 180, 0);
  gemm_mfma<0, float, bf16><<<dim3(256, 12), 256, 0, stream>>>(xd, vwt, v_b, nullptr, vb, 720, 720, 720, 736, 720, 0);
  attn_kernel<<<3072, 256, 0, stream>>>(qb, kb, vb, bias_f, xw);
  idwt_kernel<<<98304, 256, 0, stream>>>(xw, xr);
  gemm_mfma<1, float, bf16><<<dim3(1024, 3), 256, 0, stream>>>(xr, pwt, proj_b, x, x1, 180, 192, 192, 192, 180, 180);
  ln_kernel<<<32768, 256, 0, stream>>>(x1, n2w, n2b, yb);
  gemm_mfma<2, float, bf16><<<dim3(1024, 6), 256, 0, stream>>>(yb, f1wt, fc1_b, nullptr, hb, 360, 192, 192, 192, 360, 0);
  gemm_mfma<1, bf16, float><<<dim3(1024, 3), 256, 0, stream>>>(hb, f2wt, fc2_b, x1, out, 180, 360, 360, 384, 180, 180);
}